// Round 1
// baseline (777.809 us; speedup 1.0000x reference)
//
#include <hip/hip_runtime.h>

// AreaSelfAttention fused kernel for MI355X (gfx950).
// x:(4,256,252,252) fp32 -> pad to 256x256 -> 8x8 windows -> per-window
// q,k(32xP),v(256xP) 1x1 convs, S=q^T k, softmax rows, O=V P^T, out=gamma*O+x.
// One workgroup (4 waves) per window; 4096 windows.

#define HH 252
#define WW 252
#define CC 256

typedef __attribute__((ext_vector_type(8))) short bf8;     // 8 bf16 in 4 VGPRs
typedef __attribute__((ext_vector_type(4))) float f32x4;

__device__ __forceinline__ short f2bf(float f) {
    union { float f; unsigned u; } v; v.f = f;
    unsigned u = v.u;
    unsigned r = (u + 0x7fffu + ((u >> 16) & 1u)) >> 16;   // RNE
    return (short)r;
}

// Convert Wq (32x256), Wk (32x256), Wv (256x256) fp32 row-major [o][c] into
// bf16 laid out in MFMA A-fragment order:
//   frag (mt,kt), lane l, elem j  ->  W[mt*16 + (l&15)][kt*32 + (l>>4)*8 + j]
// stored at ((mt*8+kt)*64 + l)*8 + j. WqF at 0, WkF at 8192, WvF at 16384.
__global__ __launch_bounds__(256) void prep_weights(
        const float* __restrict__ Wq, const float* __restrict__ Wk,
        const float* __restrict__ Wv, short* __restrict__ wf) {
    int t = blockIdx.x * 256 + threadIdx.x;
    if (t >= 81920) return;
    const float* W; int off, base;
    if (t < 8192)       { W = Wq; off = t;         base = 0; }
    else if (t < 16384) { W = Wk; off = t - 8192;  base = 8192; }
    else                { W = Wv; off = t - 16384; base = 16384; }
    int j = off & 7, l = (off >> 3) & 63, tile = off >> 9;
    int kt = tile & 7, mt = tile >> 3;
    int m = mt * 16 + (l & 15);
    int k = kt * 32 + ((l >> 4) * 8) + j;
    wf[base + off] = f2bf(W[m * 256 + k]);
}

__global__ __launch_bounds__(256) void area_attn(
        const float* __restrict__ x, const short* __restrict__ wf,
        const float* __restrict__ bq, const float* __restrict__ bk,
        const float* __restrict__ bv, const float* __restrict__ gamma,
        float* __restrict__ out) {
    // xs: X as bf16 [p=0..63][c=0..255], row padded to 264 (528 B, 16B-aligned).
    // Reused as V ([p][c]) after the QKV GEMMs are done with X.
    __shared__ short xs[64 * 264];   // 33792 B
    __shared__ short qs[64 * 40];    // q^T: [pos][cr], row 80 B
    __shared__ short ks[64 * 40];    // k^T
    __shared__ short ps[64 * 72];    // P: [i][j], row 144 B

    const int tid  = threadIdx.x;
    const int lane = tid & 63, wv = tid >> 6;
    const int l15  = lane & 15, quad = lane >> 4;
    const int bid  = blockIdx.x;
    const int nx = bid & 31, ny = (bid >> 5) & 31, bimg = bid >> 10;
    const int hb = ny * 8, wb = nx * 8;
    const float* xb = x   + (size_t)bimg * CC * HH * WW;
    float*       ob = out + (size_t)bimg * CC * HH * WW;

    // ---- phase 1: global x -> LDS bf16 xs[p][c], zero-padded outside image
    {
        int dx = tid & 7, dy = (tid >> 3) & 7, cg = tid >> 6;
        int p = dy * 8 + dx;
        int h = hb + dy, w = wb + dx;
        bool inb = (h < HH) && (w < WW);
        const float* src = xb + (size_t)h * WW + w;
        for (int it = 0; it < 16; ++it) {
            int c0 = it * 16 + cg * 4;
            float f0 = inb ? src[(size_t)(c0 + 0) * HH * WW] : 0.f;
            float f1 = inb ? src[(size_t)(c0 + 1) * HH * WW] : 0.f;
            float f2 = inb ? src[(size_t)(c0 + 2) * HH * WW] : 0.f;
            float f3 = inb ? src[(size_t)(c0 + 3) * HH * WW] : 0.f;
            short4 pk;
            pk.x = f2bf(f0); pk.y = f2bf(f1); pk.z = f2bf(f2); pk.w = f2bf(f3);
            *reinterpret_cast<short4*>(&xs[p * 264 + c0]) = pk;
        }
    }
    __syncthreads();

    const f32x4 zero4 = {0.f, 0.f, 0.f, 0.f};

    // ---- phase 2a: Q/K GEMM. waves 0,1 -> Q (mt=wv&1); waves 2,3 -> K.
    {
        const bool isK = (wv >> 1) != 0;
        const int mt = wv & 1;
        const short* WF = wf + (isK ? 8192 : 0);
        const float* bias = isK ? bk : bq;
        f32x4 acc[4];
        for (int nt = 0; nt < 4; ++nt) acc[nt] = zero4;
        for (int kt = 0; kt < 8; ++kt) {
            bf8 a = *reinterpret_cast<const bf8*>(WF + ((mt * 8 + kt) * 64 + lane) * 8);
            for (int nt = 0; nt < 4; ++nt) {
                bf8 b = *reinterpret_cast<const bf8*>(
                    &xs[(nt * 16 + l15) * 264 + kt * 32 + quad * 8]);
                acc[nt] = __builtin_amdgcn_mfma_f32_16x16x32_bf16(a, b, acc[nt], 0, 0, 0);
            }
        }
        int cb = mt * 16 + quad * 4;
        float bi0 = bias[cb + 0], bi1 = bias[cb + 1];
        float bi2 = bias[cb + 2], bi3 = bias[cb + 3];
        short* dst = isK ? ks : qs;
        for (int nt = 0; nt < 4; ++nt) {
            int pos = nt * 16 + l15;
            short4 pk;
            pk.x = f2bf(acc[nt][0] + bi0);
            pk.y = f2bf(acc[nt][1] + bi1);
            pk.z = f2bf(acc[nt][2] + bi2);
            pk.w = f2bf(acc[nt][3] + bi3);
            *reinterpret_cast<short4*>(&dst[pos * 40 + cb]) = pk;
        }
    }

    // ---- phase 2b: V GEMM. wave w owns output channels [64w, 64w+64).
    f32x4 vacc[4][4];
    for (int mi = 0; mi < 4; ++mi)
        for (int nt = 0; nt < 4; ++nt) vacc[mi][nt] = zero4;
    {
        const short* WF = wf + 16384;
        for (int kt = 0; kt < 8; ++kt) {
            bf8 a[4];
            for (int mi = 0; mi < 4; ++mi)
                a[mi] = *reinterpret_cast<const bf8*>(
                    WF + (((wv * 4 + mi) * 8 + kt) * 64 + lane) * 8);
            for (int nt = 0; nt < 4; ++nt) {
                bf8 b = *reinterpret_cast<const bf8*>(
                    &xs[(nt * 16 + l15) * 264 + kt * 32 + quad * 8]);
                for (int mi = 0; mi < 4; ++mi)
                    vacc[mi][nt] = __builtin_amdgcn_mfma_f32_16x16x32_bf16(
                        a[mi], b, vacc[mi][nt], 0, 0, 0);
            }
        }
    }
    __syncthreads();   // all X reads done; qs/ks visible to everyone

    // ---- write V (+bias, bf16) into the xs buffer: vs[p][c], row 264
    for (int mi = 0; mi < 4; ++mi) {
        int cb = (wv * 4 + mi) * 16 + quad * 4;
        float b0 = bv[cb + 0], b1 = bv[cb + 1], b2 = bv[cb + 2], b3 = bv[cb + 3];
        for (int nt = 0; nt < 4; ++nt) {
            int pos = nt * 16 + l15;
            short4 pk;
            pk.x = f2bf(vacc[mi][nt][0] + b0);
            pk.y = f2bf(vacc[mi][nt][1] + b1);
            pk.z = f2bf(vacc[mi][nt][2] + b2);
            pk.w = f2bf(vacc[mi][nt][3] + b3);
            *reinterpret_cast<short4*>(&xs[pos * 264 + cb]) = pk;
        }
    }

    // ---- S = q^T k (M=i, N=j, K=32), softmax rows, P -> LDS bf16
    {
        f32x4 sacc[4];
        bf8 aq = *reinterpret_cast<const bf8*>(&qs[(wv * 16 + l15) * 40 + quad * 8]);
        for (int nt = 0; nt < 4; ++nt) {
            bf8 bk8 = *reinterpret_cast<const bf8*>(&ks[(nt * 16 + l15) * 40 + quad * 8]);
            sacc[nt] = __builtin_amdgcn_mfma_f32_16x16x32_bf16(aq, bk8, zero4, 0, 0, 0);
        }
        for (int r = 0; r < 4; ++r) {
            float mx = fmaxf(fmaxf(sacc[0][r], sacc[1][r]),
                             fmaxf(sacc[2][r], sacc[3][r]));
            for (int m = 1; m < 16; m <<= 1) mx = fmaxf(mx, __shfl_xor(mx, m, 64));
            float e0 = __expf(sacc[0][r] - mx);
            float e1 = __expf(sacc[1][r] - mx);
            float e2 = __expf(sacc[2][r] - mx);
            float e3 = __expf(sacc[3][r] - mx);
            float sum = e0 + e1 + e2 + e3;
            for (int m = 1; m < 16; m <<= 1) sum += __shfl_xor(sum, m, 64);
            float inv = 1.f / sum;
            int i = wv * 16 + quad * 4 + r;
            ps[i * 72 +  0 + l15] = f2bf(e0 * inv);
            ps[i * 72 + 16 + l15] = f2bf(e1 * inv);
            ps[i * 72 + 32 + l15] = f2bf(e2 * inv);
            ps[i * 72 + 48 + l15] = f2bf(e3 * inv);
        }
    }
    __syncthreads();   // vs + ps ready

    // ---- O = V P^T (M=c 256, N=i 64, K=j 64). wave w owns c in [64w,64w+64).
    f32x4 oacc[4][4];
    for (int mi = 0; mi < 4; ++mi)
        for (int nt = 0; nt < 4; ++nt) oacc[mi][nt] = zero4;
    for (int kt = 0; kt < 2; ++kt) {
        bf8 av[4];
        for (int mi = 0; mi < 4; ++mi) {
            int cidx = (wv * 4 + mi) * 16 + l15;
            bf8 a;
            for (int jj = 0; jj < 8; ++jj)
                a[jj] = xs[(kt * 32 + quad * 8 + jj) * 264 + cidx];
            av[mi] = a;
        }
        for (int nt = 0; nt < 4; ++nt) {
            bf8 bp = *reinterpret_cast<const bf8*>(
                &ps[(nt * 16 + l15) * 72 + kt * 32 + quad * 8]);
            for (int mi = 0; mi < 4; ++mi)
                oacc[mi][nt] = __builtin_amdgcn_mfma_f32_16x16x32_bf16(
                    av[mi], bp, oacc[mi][nt], 0, 0, 0);
        }
    }

    // ---- epilogue: out = gamma*O + x on the valid 252x252 crop
    float g = gamma[0];
    for (int mi = 0; mi < 4; ++mi) {
        for (int r = 0; r < 4; ++r) {
            int c = (wv * 4 + mi) * 16 + quad * 4 + r;
            const float* xrow = xb + (size_t)c * HH * WW;
            float*       orow = ob + (size_t)c * HH * WW;
            for (int nt = 0; nt < 4; ++nt) {
                int pos = nt * 16 + l15;
                int h = hb + (pos >> 3), w = wb + (pos & 7);
                if (h < HH && w < WW) {
                    size_t idx = (size_t)h * WW + w;
                    orow[idx] = g * oacc[mi][nt][r] + xrow[idx];
                }
            }
        }
    }
}

extern "C" void kernel_launch(void* const* d_in, const int* in_sizes, int n_in,
                              void* d_out, int out_size, void* d_ws, size_t ws_size,
                              hipStream_t stream) {
    const float* x  = (const float*)d_in[0];
    const float* Wq = (const float*)d_in[1];
    const float* bq = (const float*)d_in[2];
    const float* Wk = (const float*)d_in[3];
    const float* bk = (const float*)d_in[4];
    const float* Wv = (const float*)d_in[5];
    const float* bv = (const float*)d_in[6];
    const float* gm = (const float*)d_in[7];
    short* wf = (short*)d_ws;   // 163840 B of bf16 weight fragments

    prep_weights<<<320, 256, 0, stream>>>(Wq, Wk, Wv, wf);
    area_attn<<<4096, 256, 0, stream>>>(x, wf, bq, bk, bv, gm, (float*)d_out);
}

// Round 2
// 625.568 us; speedup vs baseline: 1.2434x; 1.2434x over previous
//
#include <hip/hip_runtime.h>

// AreaSelfAttention fused kernel for MI355X (gfx950).
// x:(4,256,252,252) fp32 -> pad to 256x256 -> 8x8 windows -> per-window
// q,k(32xP),v(256xP) 1x1 convs, S=q^T k, softmax rows, O=V P^T, out=gamma*O+x.
// One workgroup (4 waves) per window; 4096 windows.
// R2: XCD-aware block swizzle (window-row per XCD, nx innermost) so cache
// lines shared by adjacent windows live in ONE XCD's L2 (fetch once, merge
// partial writes); float4 phase-1 staging loads.

#define HH 252
#define WW 252
#define CC 256
#define HW (HH * WW)

typedef __attribute__((ext_vector_type(8))) short bf8;     // 8 bf16 in 4 VGPRs
typedef __attribute__((ext_vector_type(4))) float f32x4;

__device__ __forceinline__ short f2bf(float f) {
    union { float f; unsigned u; } v; v.f = f;
    unsigned u = v.u;
    unsigned r = (u + 0x7fffu + ((u >> 16) & 1u)) >> 16;   // RNE
    return (short)r;
}

// Convert Wq (32x256), Wk (32x256), Wv (256x256) fp32 row-major [o][c] into
// bf16 laid out in MFMA A-fragment order:
//   frag (mt,kt), lane l, elem j  ->  W[mt*16 + (l&15)][kt*32 + (l>>4)*8 + j]
// stored at ((mt*8+kt)*64 + l)*8 + j. WqF at 0, WkF at 8192, WvF at 16384.
__global__ __launch_bounds__(256) void prep_weights(
        const float* __restrict__ Wq, const float* __restrict__ Wk,
        const float* __restrict__ Wv, short* __restrict__ wf) {
    int t = blockIdx.x * 256 + threadIdx.x;
    if (t >= 81920) return;
    const float* W; int off, base;
    if (t < 8192)       { W = Wq; off = t;         base = 0; }
    else if (t < 16384) { W = Wk; off = t - 8192;  base = 8192; }
    else                { W = Wv; off = t - 16384; base = 16384; }
    int j = off & 7, l = (off >> 3) & 63, tile = off >> 9;
    int kt = tile & 7, mt = tile >> 3;
    int m = mt * 16 + (l & 15);
    int k = kt * 32 + ((l >> 4) * 8) + j;
    wf[base + off] = f2bf(W[m * 256 + k]);
}

__global__ __launch_bounds__(256) void area_attn(
        const float* __restrict__ x, const short* __restrict__ wf,
        const float* __restrict__ bq, const float* __restrict__ bk,
        const float* __restrict__ bv, const float* __restrict__ gamma,
        float* __restrict__ out) {
    // xs: X as bf16 [p=0..63][c=0..255], row padded to 264 (528 B, 16B-aligned).
    // Reused as V ([p][c]) after the QKV GEMMs are done with X.
    __shared__ short xs[64 * 264];   // 33792 B
    __shared__ short qs[64 * 40];    // q^T: [pos][cr], row 80 B
    __shared__ short ks[64 * 40];    // k^T
    __shared__ short ps[64 * 72];    // P: [i][j], row 144 B

    const int tid  = threadIdx.x;
    const int lane = tid & 63, wv = tid >> 6;
    const int l15  = lane & 15, quad = lane >> 4;

    // XCD-aware swizzle: xcd = bid&7 (HW round-robin). Each XCD owns whole
    // window-rows (all 32 nx consecutive) so 64B lines spanning adjacent
    // windows are fetched once into that XCD's L2 and partial 32B writes
    // merge into full lines there. nx is the innermost sweep per XCD.
    const int bid  = blockIdx.x;
    const int xcd  = bid & 7;
    const int j    = bid >> 3;          // 0..511
    const int nx   = j & 31;
    const int grow = (j >> 5) * 8 + xcd; // 0..127 global window-row id
    const int bimg = grow >> 5;
    const int ny   = grow & 31;
    const int hb = ny * 8, wb = nx * 8;
    const float* xb = x   + (size_t)bimg * CC * HW;
    float*       ob = out + (size_t)bimg * CC * HW;

    // ---- phase 1: global x -> LDS bf16 xs[p][c], zero-padded outside image.
    // float4 loads along w; 252 = 248+4 means edge float4s are fully OOB
    // (never partial), so a single predicate per thread suffices.
    {
        int half = tid & 1, dy = (tid >> 1) & 7, cg = tid >> 4;  // cg 0..15
        int h = hb + dy;
        int w0 = wb + half * 4;
        bool inb = (h < HH) && (w0 < WW);
        const float* src = xb + (size_t)h * WW + w0;
        int p0 = dy * 8 + half * 4;
        for (int it = 0; it < 16; ++it) {
            int c = it * 16 + cg;
            float4 f;
            if (inb) f = *reinterpret_cast<const float4*>(src + (size_t)c * HW);
            else     f = make_float4(0.f, 0.f, 0.f, 0.f);
            xs[(p0 + 0) * 264 + c] = f2bf(f.x);
            xs[(p0 + 1) * 264 + c] = f2bf(f.y);
            xs[(p0 + 2) * 264 + c] = f2bf(f.z);
            xs[(p0 + 3) * 264 + c] = f2bf(f.w);
        }
    }
    __syncthreads();

    const f32x4 zero4 = {0.f, 0.f, 0.f, 0.f};

    // ---- phase 2a: Q/K GEMM. waves 0,1 -> Q (mt=wv&1); waves 2,3 -> K.
    {
        const bool isK = (wv >> 1) != 0;
        const int mt = wv & 1;
        const short* WF = wf + (isK ? 8192 : 0);
        const float* bias = isK ? bk : bq;
        f32x4 acc[4];
        for (int nt = 0; nt < 4; ++nt) acc[nt] = zero4;
        for (int kt = 0; kt < 8; ++kt) {
            bf8 a = *reinterpret_cast<const bf8*>(WF + ((mt * 8 + kt) * 64 + lane) * 8);
            for (int nt = 0; nt < 4; ++nt) {
                bf8 b = *reinterpret_cast<const bf8*>(
                    &xs[(nt * 16 + l15) * 264 + kt * 32 + quad * 8]);
                acc[nt] = __builtin_amdgcn_mfma_f32_16x16x32_bf16(a, b, acc[nt], 0, 0, 0);
            }
        }
        int cb = mt * 16 + quad * 4;
        float bi0 = bias[cb + 0], bi1 = bias[cb + 1];
        float bi2 = bias[cb + 2], bi3 = bias[cb + 3];
        short* dst = isK ? ks : qs;
        for (int nt = 0; nt < 4; ++nt) {
            int pos = nt * 16 + l15;
            short4 pk;
            pk.x = f2bf(acc[nt][0] + bi0);
            pk.y = f2bf(acc[nt][1] + bi1);
            pk.z = f2bf(acc[nt][2] + bi2);
            pk.w = f2bf(acc[nt][3] + bi3);
            *reinterpret_cast<short4*>(&dst[pos * 40 + cb]) = pk;
        }
    }

    // ---- phase 2b: V GEMM. wave w owns output channels [64w, 64w+64).
    f32x4 vacc[4][4];
    for (int mi = 0; mi < 4; ++mi)
        for (int nt = 0; nt < 4; ++nt) vacc[mi][nt] = zero4;
    {
        const short* WF = wf + 16384;
        for (int kt = 0; kt < 8; ++kt) {
            bf8 a[4];
            for (int mi = 0; mi < 4; ++mi)
                a[mi] = *reinterpret_cast<const bf8*>(
                    WF + (((wv * 4 + mi) * 8 + kt) * 64 + lane) * 8);
            for (int nt = 0; nt < 4; ++nt) {
                bf8 b = *reinterpret_cast<const bf8*>(
                    &xs[(nt * 16 + l15) * 264 + kt * 32 + quad * 8]);
                for (int mi = 0; mi < 4; ++mi)
                    vacc[mi][nt] = __builtin_amdgcn_mfma_f32_16x16x32_bf16(
                        a[mi], b, vacc[mi][nt], 0, 0, 0);
            }
        }
    }
    __syncthreads();   // all X reads done; qs/ks visible to everyone

    // ---- write V (+bias, bf16) into the xs buffer: vs[p][c], row 264
    for (int mi = 0; mi < 4; ++mi) {
        int cb = (wv * 4 + mi) * 16 + quad * 4;
        float b0 = bv[cb + 0], b1 = bv[cb + 1], b2 = bv[cb + 2], b3 = bv[cb + 3];
        for (int nt = 0; nt < 4; ++nt) {
            int pos = nt * 16 + l15;
            short4 pk;
            pk.x = f2bf(vacc[mi][nt][0] + b0);
            pk.y = f2bf(vacc[mi][nt][1] + b1);
            pk.z = f2bf(vacc[mi][nt][2] + b2);
            pk.w = f2bf(vacc[mi][nt][3] + b3);
            *reinterpret_cast<short4*>(&xs[pos * 264 + cb]) = pk;
        }
    }

    // ---- S = q^T k (M=i, N=j, K=32), softmax rows, P -> LDS bf16
    {
        f32x4 sacc[4];
        bf8 aq = *reinterpret_cast<const bf8*>(&qs[(wv * 16 + l15) * 40 + quad * 8]);
        for (int nt = 0; nt < 4; ++nt) {
            bf8 bk8 = *reinterpret_cast<const bf8*>(&ks[(nt * 16 + l15) * 40 + quad * 8]);
            sacc[nt] = __builtin_amdgcn_mfma_f32_16x16x32_bf16(aq, bk8, zero4, 0, 0, 0);
        }
        for (int r = 0; r < 4; ++r) {
            float mx = fmaxf(fmaxf(sacc[0][r], sacc[1][r]),
                             fmaxf(sacc[2][r], sacc[3][r]));
            for (int m = 1; m < 16; m <<= 1) mx = fmaxf(mx, __shfl_xor(mx, m, 64));
            float e0 = __expf(sacc[0][r] - mx);
            float e1 = __expf(sacc[1][r] - mx);
            float e2 = __expf(sacc[2][r] - mx);
            float e3 = __expf(sacc[3][r] - mx);
            float sum = e0 + e1 + e2 + e3;
            for (int m = 1; m < 16; m <<= 1) sum += __shfl_xor(sum, m, 64);
            float inv = 1.f / sum;
            int i = wv * 16 + quad * 4 + r;
            ps[i * 72 +  0 + l15] = f2bf(e0 * inv);
            ps[i * 72 + 16 + l15] = f2bf(e1 * inv);
            ps[i * 72 + 32 + l15] = f2bf(e2 * inv);
            ps[i * 72 + 48 + l15] = f2bf(e3 * inv);
        }
    }
    __syncthreads();   // vs + ps ready

    // ---- O = V P^T (M=c 256, N=i 64, K=j 64). wave w owns c in [64w,64w+64).
    f32x4 oacc[4][4];
    for (int mi = 0; mi < 4; ++mi)
        for (int nt = 0; nt < 4; ++nt) oacc[mi][nt] = zero4;
    for (int kt = 0; kt < 2; ++kt) {
        bf8 av[4];
        for (int mi = 0; mi < 4; ++mi) {
            int cidx = (wv * 4 + mi) * 16 + l15;
            bf8 a;
            for (int jj = 0; jj < 8; ++jj)
                a[jj] = xs[(kt * 32 + quad * 8 + jj) * 264 + cidx];
            av[mi] = a;
        }
        for (int nt = 0; nt < 4; ++nt) {
            bf8 bp = *reinterpret_cast<const bf8*>(
                &ps[(nt * 16 + l15) * 72 + kt * 32 + quad * 8]);
            for (int mi = 0; mi < 4; ++mi)
                oacc[mi][nt] = __builtin_amdgcn_mfma_f32_16x16x32_bf16(
                    av[mi], bp, oacc[mi][nt], 0, 0, 0);
        }
    }

    // ---- epilogue: out = gamma*O + x on the valid 252x252 crop
    float g = gamma[0];
    for (int mi = 0; mi < 4; ++mi) {
        for (int r = 0; r < 4; ++r) {
            int c = (wv * 4 + mi) * 16 + quad * 4 + r;
            const float* xrow = xb + (size_t)c * HW;
            float*       orow = ob + (size_t)c * HW;
            for (int nt = 0; nt < 4; ++nt) {
                int pos = nt * 16 + l15;
                int h = hb + (pos >> 3), w = wb + (pos & 7);
                if (h < HH && w < WW) {
                    size_t idx = (size_t)h * WW + w;
                    orow[idx] = g * oacc[mi][nt][r] + xrow[idx];
                }
            }
        }
    }
}

extern "C" void kernel_launch(void* const* d_in, const int* in_sizes, int n_in,
                              void* d_out, int out_size, void* d_ws, size_t ws_size,
                              hipStream_t stream) {
    const float* x  = (const float*)d_in[0];
    const float* Wq = (const float*)d_in[1];
    const float* bq = (const float*)d_in[2];
    const float* Wk = (const float*)d_in[3];
    const float* bk = (const float*)d_in[4];
    const float* Wv = (const float*)d_in[5];
    const float* bv = (const float*)d_in[6];
    const float* gm = (const float*)d_in[7];
    short* wf = (short*)d_ws;   // 163840 B of bf16 weight fragments

    prep_weights<<<320, 256, 0, stream>>>(Wq, Wk, Wv, wf);
    area_attn<<<4096, 256, 0, stream>>>(x, wf, bq, bk, bv, gm, (float*)d_out);
}